// Round 12
// baseline (1054.071 us; speedup 1.0000x reference)
//
#include <hip/hip_runtime.h>
#include <math.h>

#define NN 50000
#define EE 800000
#define EPS 1e-5f
#define SCAN_CH 196   // ceil(NN/256)

#define NEG_BIG (-1e30f)
#define RESCALE_THR 4.0f

#define LO_SCALE 2048.0f       // 2^11 exponent shift for the f16 lo plane
#define LO_INV   (1.0f/2048.0f)

typedef unsigned short u16;
typedef _Float16 f16x8 __attribute__((ext_vector_type(8)));
typedef float f32x4 __attribute__((ext_vector_type(4)));

__device__ __forceinline__ u16 f2h(float f) {
    _Float16 h = (_Float16)f;               // v_cvt_f16_f32, RNE
    return __builtin_bit_cast(u16, h);
}
__device__ __forceinline__ float h2f(u16 u) {
    return (float)__builtin_bit_cast(_Float16, u);
}

__device__ __forceinline__ float dpp_add8(float x) {
    int t;
    t = __builtin_amdgcn_update_dpp(0, __float_as_int(x), 0xB1, 0xf, 0xf, true);
    x += __int_as_float(t);
    t = __builtin_amdgcn_update_dpp(0, __float_as_int(x), 0x4E, 0xf, 0xf, true);
    x += __int_as_float(t);
    t = __builtin_amdgcn_update_dpp(0, __float_as_int(x), 0x141, 0xf, 0xf, true);
    x += __int_as_float(t);
    return x;
}

// ---------------------------------------------------------------------------
// CSR build: histogram -> scan (partials; final scan inlined) -> scatter
// ---------------------------------------------------------------------------
__global__ void hist_kernel(const int* __restrict__ dst, int* cnt) {
    int e = blockIdx.x * blockDim.x + threadIdx.x;
    if (e < EE) atomicAdd(&cnt[dst[e]], 1);
}

__global__ void scan_part(const int* __restrict__ cnt, int* __restrict__ part) {
    __shared__ int red[256];
    int b = blockIdx.x, t = threadIdx.x;
    int i = b * SCAN_CH + t;
    int v = (t < SCAN_CH && i < NN) ? cnt[i] : 0;
    red[t] = v;
    __syncthreads();
#pragma unroll
    for (int s = 128; s; s >>= 1) {
        if (t < s) red[t] += red[t + s];
        __syncthreads();
    }
    if (t == 0) part[b] = red[0];
}

// 256 blocks: inline full scan of 256 partials (redundant per block, cheap)
// + in-block inclusive scan -> row_start & cursor. Replaces scan_block+final.
__global__ void scan_final(int* __restrict__ cntcur, const int* __restrict__ part,
                           int* __restrict__ row_start) {
    __shared__ int pbuf[2][256];
    __shared__ int buf[2][256];
    int b = blockIdx.x, t = threadIdx.x;

    // scan the 256 block-partials (inclusive) in shared memory
    int pv = part[t];
    int pp = 0;
    pbuf[0][t] = pv;
    __syncthreads();
#pragma unroll
    for (int off = 1; off < 256; off <<= 1) {
        pbuf[pp ^ 1][t] = pbuf[pp][t] + ((t >= off) ? pbuf[pp][t - off] : 0);
        __syncthreads();
        pp ^= 1;
    }
    int base = (b == 0) ? 0 : pbuf[pp][b - 1];   // exclusive offset of block b

    int i = b * SCAN_CH + t;
    int v = (t < SCAN_CH && i < NN) ? cntcur[i] : 0;
    int p = 0;
    buf[0][t] = v;
    __syncthreads();
#pragma unroll
    for (int off = 1; off < 256; off <<= 1) {
        buf[p ^ 1][t] = buf[p][t] + ((t >= off) ? buf[p][t - off] : 0);
        __syncthreads();
        p ^= 1;
    }
    if (t < SCAN_CH && i < NN) {
        int pos = base + buf[p][t] - v;      // exclusive
        row_start[i] = pos;
        cntcur[i] = pos;                     // scatter cursor
    }
    if (b == 0 && t == 0) row_start[NN] = EE;
}

__global__ void scatter_kernel(const int* __restrict__ ei, const float* __restrict__ ea,
                               int* cursor, int2* __restrict__ edge_pack) {
    int e = blockIdx.x * blockDim.x + threadIdx.x;
    if (e < EE) {
        int d = ei[EE + e];
        int pos = atomicAdd(&cursor[d], 1);
        edge_pack[pos] = make_int2(ei[e], __float_as_int(ea[e]));
    }
}

// ---------------------------------------------------------------------------
// One-time prep, fused into a single dispatch:
//   range 0: fp32 x -> f16 hi + scaled-lo planes (float4-vectorized)
//   range 1: 9 layers [Wl|Wr] -> Wt[layer][256][128] f16 hi/lo
//   range 2: layer-10 Wl/Wr [128][32] -> Wt10[64][128] f16 hi/lo
// ---------------------------------------------------------------------------
#define SPLIT_N4   (NN * 128 / 4)        // 1,600,000
#define CONVW_N    (9 * 256 * 128)       // 294,912
#define CONVW10_N  (64 * 128)            // 8,192
#define PREP_TOTAL (SPLIT_N4 + CONVW_N + CONVW10_N)

__global__ void prep_all(const float* __restrict__ x,
                         const float* __restrict__ l1Wl, const float* __restrict__ l1Wr,
                         const float* __restrict__ midWl, const float* __restrict__ midWr,
                         const float* __restrict__ l10Wl, const float* __restrict__ l10Wr,
                         u16* __restrict__ Ahi, u16* __restrict__ Alo,
                         u16* __restrict__ Wh, u16* __restrict__ Wlo,
                         u16* __restrict__ W10h, u16* __restrict__ W10lo) {
    int tid = blockIdx.x * 256 + threadIdx.x;
    if (tid < SPLIT_N4) {
        float4 v = ((const float4*)x)[tid];
        ushort4 h, l;
        h.x = f2h(v.x); l.x = f2h((v.x - h2f(h.x)) * LO_SCALE);
        h.y = f2h(v.y); l.y = f2h((v.y - h2f(h.y)) * LO_SCALE);
        h.z = f2h(v.z); l.z = f2h((v.z - h2f(h.z)) * LO_SCALE);
        h.w = f2h(v.w); l.w = f2h((v.w - h2f(h.w)) * LO_SCALE);
        ((ushort4*)Ahi)[tid] = h;
        ((ushort4*)Alo)[tid] = l;
    } else if (tid < SPLIT_N4 + CONVW_N) {
        int c = tid - SPLIT_N4;
        int L = c >> 15;
        int rem = c & 32767;
        int n = rem >> 7, k = rem & 127;
        const float* WL;
        const float* WR;
        if (L == 0) { WL = l1Wl; WR = l1Wr; }
        else {
            WL = midWl + (size_t)(L - 1) * 16384;
            WR = midWr + (size_t)(L - 1) * 16384;
        }
        float w = (n < 128) ? WL[k * 128 + n] : WR[k * 128 + (n - 128)];
        u16 h = f2h(w);
        Wh[c] = h;
        Wlo[c] = f2h((w - h2f(h)) * LO_SCALE);
    } else if (tid < PREP_TOTAL) {
        int c = tid - SPLIT_N4 - CONVW_N;
        int n = c >> 7, k = c & 127;
        float w = (n < 32) ? l10Wl[k * 32 + n] : l10Wr[k * 32 + (n - 32)];
        u16 h = f2h(w);
        W10h[c] = h;
        W10lo[c] = f2h((w - h2f(h)) * LO_SCALE);
    }
}

// ---------------------------------------------------------------------------
// MFMA f16 split GEMM (round-11 proven, frozen): LDS-shared A.
// Block = 512 thr (8 waves) computes 64 rows x all 256 cols. A (hi+lo) staged
// ONCE into padded LDS (stride 136 u16), shared by all 8 waves. B frags
// loop-invariant in regs. One barrier. Output planes C[plane][N][128].
// ---------------------------------------------------------------------------
#define ASTRIDE 136   // u16 units: 128 + 8 pad

__global__ __launch_bounds__(512) void gemm_mfma(const u16* __restrict__ Ah,
                                                 const u16* __restrict__ Al,
                                                 const u16* __restrict__ Bh,
                                                 const u16* __restrict__ Bl,
                                                 float* __restrict__ C) {
    __shared__ u16 Ahs[64 * ASTRIDE];
    __shared__ u16 Als[64 * ASTRIDE];

    int t    = threadIdx.x;
    int w    = t >> 6;               // wave 0..7
    int lane = t & 63;
    int lr = lane & 15;
    int kg = lane >> 4;
    int rowbase = blockIdx.x * 64;

    int colbase = w * 32;            // 0..224 within Wt[256]
    int y    = colbase >> 7;         // output plane
    int colb = colbase & 127;        // col within plane
    f16x8 bh[2][4], bl[2][4];
#pragma unroll
    for (int ct = 0; ct < 2; ++ct) {
        size_t boff = (size_t)(colbase + ct * 16 + lr) * 128 + (size_t)(kg * 8);
#pragma unroll
        for (int ks = 0; ks < 4; ++ks) {
            bh[ct][ks] = *(const f16x8*)(Bh + boff + ks * 32);
            bl[ct][ks] = *(const f16x8*)(Bl + boff + ks * 32);
        }
    }

#pragma unroll
    for (int i = 0; i < 2; ++i) {
        int c = t + i * 512;                  // 0..1023
        int row  = c >> 4;                    // 0..63 (16 chunks per row)
        int colu = (c & 15) * 8;              // u16 offset within row
        int grow = rowbase + row; if (grow >= NN) grow = NN - 1;
        size_t go = (size_t)grow * 128 + colu;
        *(f16x8*)(Ahs + row * ASTRIDE + colu) = *(const f16x8*)(Ah + go);
        *(f16x8*)(Als + row * ASTRIDE + colu) = *(const f16x8*)(Al + go);
    }
    __syncthreads();

    float* Cp = C + (size_t)y * ((size_t)NN * 128);

#pragma unroll
    for (int rt = 0; rt < 4; ++rt) {
        int abase = (rt * 16 + lr) * ASTRIDE + kg * 8;
        f16x8 ah[4], al[4];
#pragma unroll
        for (int ks = 0; ks < 4; ++ks) {
            ah[ks] = *(const f16x8*)(Ahs + abase + ks * 32);
            al[ks] = *(const f16x8*)(Als + abase + ks * 32);
        }

        f32x4 aH[2], aL[2];
#pragma unroll
        for (int ct = 0; ct < 2; ++ct) {
            aH[ct] = (f32x4){0.f, 0.f, 0.f, 0.f};
            aL[ct] = (f32x4){0.f, 0.f, 0.f, 0.f};
        }
#pragma unroll
        for (int ks = 0; ks < 4; ++ks) {
#pragma unroll
            for (int ct = 0; ct < 2; ++ct) {
                aH[ct] = __builtin_amdgcn_mfma_f32_16x16x32_f16(ah[ks], bh[ct][ks], aH[ct], 0, 0, 0);
                aL[ct] = __builtin_amdgcn_mfma_f32_16x16x32_f16(al[ks], bh[ct][ks], aL[ct], 0, 0, 0);
                aL[ct] = __builtin_amdgcn_mfma_f32_16x16x32_f16(ah[ks], bl[ct][ks], aL[ct], 0, 0, 0);
            }
        }

        int crow0 = rowbase + rt * 16 + kg * 4;
#pragma unroll
        for (int ct = 0; ct < 2; ++ct) {
            float* cp = Cp + (size_t)crow0 * 128 + colb + ct * 16 + lr;
#pragma unroll
            for (int r = 0; r < 4; ++r) {
                if (crow0 + r < NN)
                    cp[(size_t)r * 128] = fmaf(aL[ct][r], LO_INV, aH[ct][r]);
            }
        }
    }
}

// ---------------------------------------------------------------------------
// Layer-10 GEMM via MFMA (64 cols): C[N][64] fp32 = A[N][128] @ Wt10^T.
// ---------------------------------------------------------------------------
__global__ __launch_bounds__(256) void gemm_mfma_l10(const u16* __restrict__ Ah,
                                                     const u16* __restrict__ Al,
                                                     const u16* __restrict__ Bh,
                                                     const u16* __restrict__ Bl,
                                                     float* __restrict__ C) {
    int w    = threadIdx.x >> 6;
    int lane = threadIdx.x & 63;
    int lr = lane & 15;
    int kg = lane >> 4;
    int rowbase = blockIdx.x * 64;
    int colb = w * 16;                      // 4 waves cover 64 cols

    f16x8 bh[4], bl[4];
    {
        size_t boff = (size_t)(colb + lr) * 128 + (size_t)(kg * 8);
#pragma unroll
        for (int ks = 0; ks < 4; ++ks) {
            bh[ks] = *(const f16x8*)(Bh + boff + ks * 32);
            bl[ks] = *(const f16x8*)(Bl + boff + ks * 32);
        }
    }

    auto aoff_of = [&](int rt) {
        int arow = rowbase + rt * 16 + lr;
        if (arow >= NN) arow = NN - 1;
        return (size_t)arow * 128 + (size_t)(kg * 8);
    };
    f16x8 ahc[4], alc[4], ahn[4], aln[4];
    {
        size_t ao = aoff_of(0);
#pragma unroll
        for (int ks = 0; ks < 4; ++ks) {
            ahc[ks] = *(const f16x8*)(Ah + ao + ks * 32);
            alc[ks] = *(const f16x8*)(Al + ao + ks * 32);
        }
    }

#pragma unroll
    for (int rt = 0; rt < 4; ++rt) {
        if (rt < 3) {
            size_t ao = aoff_of(rt + 1);
#pragma unroll
            for (int ks = 0; ks < 4; ++ks) {
                ahn[ks] = *(const f16x8*)(Ah + ao + ks * 32);
                aln[ks] = *(const f16x8*)(Al + ao + ks * 32);
            }
        }

        f32x4 aH = (f32x4){0.f, 0.f, 0.f, 0.f};
        f32x4 aL = (f32x4){0.f, 0.f, 0.f, 0.f};
#pragma unroll
        for (int ks = 0; ks < 4; ++ks) {
            aH = __builtin_amdgcn_mfma_f32_16x16x32_f16(ahc[ks], bh[ks], aH, 0, 0, 0);
            aL = __builtin_amdgcn_mfma_f32_16x16x32_f16(alc[ks], bh[ks], aL, 0, 0, 0);
            aL = __builtin_amdgcn_mfma_f32_16x16x32_f16(ahc[ks], bl[ks], aL, 0, 0, 0);
        }

        int crow0 = rowbase + rt * 16 + kg * 4;
        float* cp = C + (size_t)crow0 * 64 + colb + lr;
#pragma unroll
        for (int r = 0; r < 4; ++r) {
            if (crow0 + r < NN)
                cp[(size_t)r * 64] = fmaf(aL[r], LO_INV, aH[r]);
        }

        if (rt < 3) {
#pragma unroll
            for (int ks = 0; ks < 4; ++ks) { ahc[ks] = ahn[ks]; alc[ks] = aln[ks]; }
        }
    }
}

// ---------------------------------------------------------------------------
// Node kernel layers 1-9 (round-9 structure; round-12: fused single ballot
// for the two softmax states per 4-edge group — slow path rescales both,
// always-valid). One wave per node, half-wave per edge, 4 ch/lane.
// ---------------------------------------------------------------------------
__global__ __launch_bounds__(256) void node_agg_128(const float* __restrict__ xlr,
                                                    const int* __restrict__ row_start,
                                                    const int2* __restrict__ epack,
                                                    const float* __restrict__ We,
                                                    const float* __restrict__ att,
                                                    const float* __restrict__ bias,
                                                    const float* __restrict__ bng,
                                                    const float* __restrict__ bnb,
                                                    const float* __restrict__ bnm,
                                                    const float* __restrict__ bnv,
                                                    u16* __restrict__ ahi,
                                                    u16* __restrict__ alo) {
    int node = (blockIdx.x * blockDim.x + threadIdx.x) >> 6;
    int lane = threadIdx.x & 63;
    if (node >= NN) return;
    int half = lane >> 5;
    int c0   = (lane & 31) << 2;

    const float* xlp = xlr;                           // xl plane [N][128]
    const float* xrp = xlr + (size_t)NN * 128;        // xr plane [N][128]

    const float L2E = 1.44269504f;
    const float4 xr4 = *(const float4*)(xrp + (size_t)node * 128 + c0);
    const float4 we4 = *(const float4*)(We + c0);
    const float4 at4 = *(const float4*)(att + c0);
    float4 a6, a4;
    a6.x = 0.6f * L2E * at4.x; a4.x = 0.4f * L2E * at4.x;
    a6.y = 0.6f * L2E * at4.y; a4.y = 0.4f * L2E * at4.y;
    a6.z = 0.6f * L2E * at4.z; a4.z = 0.4f * L2E * at4.z;
    a6.w = 0.6f * L2E * at4.w; a4.w = 0.4f * L2E * at4.w;

    int beg = row_start[node], end = row_start[node + 1];
    int lastE = end - 1;

    float mx0 = NEG_BIG, sm0 = 0.f;
    float mx1 = NEG_BIG, sm1 = 0.f;
    float4 ac0 = make_float4(0.f, 0.f, 0.f, 0.f);
    float4 ac1 = make_float4(0.f, 0.f, 0.f, 0.f);

    auto score = [&](float eav, const float4& xv) -> float {
        float m0 = xv.x + fmaf(eav, we4.x, xr4.x);
        float m1 = xv.y + fmaf(eav, we4.y, xr4.y);
        float m2 = xv.z + fmaf(eav, we4.z, xr4.z);
        float m3 = xv.w + fmaf(eav, we4.w, xr4.w);
        float p = fmaf(a6.x, m0, a4.x * fabsf(m0));
        p = fmaf(a6.y, m1, fmaf(a4.y, fabsf(m1), p));
        p = fmaf(a6.z, m2, fmaf(a4.z, fabsf(m2), p));
        p = fmaf(a6.w, m3, fmaf(a4.w, fabsf(m3), p));
        return dpp_add8(p);
    };

    auto upd = [&](float& mx, float& sm, float4& ac, float p, const float4& xv) {
        float d = p - mx;
        if (__ballot(d > RESCALE_THR)) {
            float nm = fmaxf(mx, p);
            float sc = exp2f(mx - nm);
            float w  = exp2f(p - nm);
            sm = fmaf(sm, sc, w);
            ac.x = fmaf(ac.x, sc, w * xv.x);
            ac.y = fmaf(ac.y, sc, w * xv.y);
            ac.z = fmaf(ac.z, sc, w * xv.z);
            ac.w = fmaf(ac.w, sc, w * xv.w);
            mx = nm;
        } else {
            float w = exp2f(d);
            sm += w;
            ac.x = fmaf(w, xv.x, ac.x);
            ac.y = fmaf(w, xv.y, ac.y);
            ac.z = fmaf(w, xv.z, ac.z);
            ac.w = fmaf(w, xv.w, ac.w);
        }
    };

    int j = beg;
    for (; j + 3 < end; j += 4) {
        int2 pkA = epack[j + half];
        int2 pkB = epack[j + 2 + half];
        float4 xA = *(const float4*)(xlp + ((size_t)pkA.x << 7) + c0);
        float4 xB = *(const float4*)(xlp + ((size_t)pkB.x << 7) + c0);
        float pA = score(__int_as_float(pkA.y), xA);
        float pB = score(__int_as_float(pkB.y), xB);
        float dA = pA - mx0;
        float dB = pB - mx1;
        // single ballot for both states; slow path rescales both (valid)
        if (__ballot(fmaxf(dA, dB) > RESCALE_THR)) {
            float nmA = fmaxf(mx0, pA);
            float scA = exp2f(mx0 - nmA);
            float wA  = exp2f(pA - nmA);
            sm0 = fmaf(sm0, scA, wA);
            ac0.x = fmaf(ac0.x, scA, wA * xA.x);
            ac0.y = fmaf(ac0.y, scA, wA * xA.y);
            ac0.z = fmaf(ac0.z, scA, wA * xA.z);
            ac0.w = fmaf(ac0.w, scA, wA * xA.w);
            mx0 = nmA;
            float nmB = fmaxf(mx1, pB);
            float scB = exp2f(mx1 - nmB);
            float wB  = exp2f(pB - nmB);
            sm1 = fmaf(sm1, scB, wB);
            ac1.x = fmaf(ac1.x, scB, wB * xB.x);
            ac1.y = fmaf(ac1.y, scB, wB * xB.y);
            ac1.z = fmaf(ac1.z, scB, wB * xB.z);
            ac1.w = fmaf(ac1.w, scB, wB * xB.w);
            mx1 = nmB;
        } else {
            float wA = exp2f(dA);
            sm0 += wA;
            ac0.x = fmaf(wA, xA.x, ac0.x);
            ac0.y = fmaf(wA, xA.y, ac0.y);
            ac0.z = fmaf(wA, xA.z, ac0.z);
            ac0.w = fmaf(wA, xA.w, ac0.w);
            float wB = exp2f(dB);
            sm1 += wB;
            ac1.x = fmaf(wB, xB.x, ac1.x);
            ac1.y = fmaf(wB, xB.y, ac1.y);
            ac1.z = fmaf(wB, xB.z, ac1.z);
            ac1.w = fmaf(wB, xB.w, ac1.w);
        }
    }
    if (j < end) {   // tail: 1..3 real edges; dead slots forced NEG_BIG
        int jeA = j + half;       bool dA = jeA > lastE; if (dA) jeA = lastE;
        int jeB = j + 2 + half;   bool dB = jeB > lastE; if (dB) jeB = lastE;
        int2 pkA = epack[jeA];
        int2 pkB = epack[jeB];
        float4 xA = *(const float4*)(xlp + ((size_t)pkA.x << 7) + c0);
        float4 xB = *(const float4*)(xlp + ((size_t)pkB.x << 7) + c0);
        float pA = score(__int_as_float(pkA.y), xA);
        float pB = score(__int_as_float(pkB.y), xB);
        pA = dA ? NEG_BIG : pA;
        pB = dB ? NEG_BIG : pB;
        upd(mx0, sm0, ac0, pA, xA);
        upd(mx1, sm1, ac1, pB, xB);
    }

    // merge the 2 states in-lane
    float Mx = fmaxf(mx0, mx1);
    float s0 = exp2f(mx0 - Mx), s1 = exp2f(mx1 - Mx);
    float sm = fmaf(sm0, s0, sm1 * s1);
    float4 ac;
    ac.x = fmaf(ac0.x, s0, ac1.x * s1);
    ac.y = fmaf(ac0.y, s0, ac1.y * s1);
    ac.z = fmaf(ac0.z, s0, ac1.z * s1);
    ac.w = fmaf(ac0.w, s0, ac1.w * s1);

    // merge across halves (lanes l and l+32 hold the same channels)
    float  Mo  = __shfl_xor(Mx, 32);
    float  smo = __shfl_xor(sm, 32);
    float4 aco;
    aco.x = __shfl_xor(ac.x, 32);
    aco.y = __shfl_xor(ac.y, 32);
    aco.z = __shfl_xor(ac.z, 32);
    aco.w = __shfl_xor(ac.w, 32);
    float Mn = fmaxf(Mx, Mo);
    float ss = exp2f(Mx - Mn), so = exp2f(Mo - Mn);
    sm   = fmaf(sm, ss, smo * so);
    ac.x = fmaf(ac.x, ss, aco.x * so);
    ac.y = fmaf(ac.y, ss, aco.y * so);
    ac.z = fmaf(ac.z, ss, aco.z * so);
    ac.w = fmaf(ac.w, ss, aco.w * so);

    if (half == 0) {
        float inv = 1.f / (sm + 1e-16f);
        const float4 b4  = *(const float4*)(bias + c0);
        const float4 g4  = *(const float4*)(bng + c0);
        const float4 bb4 = *(const float4*)(bnb + c0);
        const float4 m4  = *(const float4*)(bnm + c0);
        const float4 v4  = *(const float4*)(bnv + c0);
        float4 y;
        y.x = fmaxf(fmaf(ac.x, inv, b4.x), 0.f);
        y.y = fmaxf(fmaf(ac.y, inv, b4.y), 0.f);
        y.z = fmaxf(fmaf(ac.z, inv, b4.z), 0.f);
        y.w = fmaxf(fmaf(ac.w, inv, b4.w), 0.f);
        y.x = (y.x - m4.x) * rsqrtf(v4.x + EPS) * g4.x + bb4.x;
        y.y = (y.y - m4.y) * rsqrtf(v4.y + EPS) * g4.y + bb4.y;
        y.z = (y.z - m4.z) * rsqrtf(v4.z + EPS) * g4.z + bb4.z;
        y.w = (y.w - m4.w) * rsqrtf(v4.w + EPS) * g4.w + bb4.w;

        ushort4 hh, ll;
        hh.x = f2h(y.x); ll.x = f2h((y.x - h2f(hh.x)) * LO_SCALE);
        hh.y = f2h(y.y); ll.y = f2h((y.y - h2f(hh.y)) * LO_SCALE);
        hh.z = f2h(y.z); ll.z = f2h((y.z - h2f(hh.z)) * LO_SCALE);
        hh.w = f2h(y.w); ll.w = f2h((y.w - h2f(hh.w)) * LO_SCALE);
        *(ushort4*)(ahi + (size_t)node * 128 + c0) = hh;
        *(ushort4*)(alo + (size_t)node * 128 + c0) = ll;
    }
}

// ---------------------------------------------------------------------------
// Layer 10: half-wave per node, 8 lanes/edge x 4 ch/lane, 4 edge slots,
// float4 gathers, dpp_add8 head reduce, defer-max, fused linear.
// ---------------------------------------------------------------------------
__global__ __launch_bounds__(256) void node_agg_l10(const float* __restrict__ xlr,
                                                    const int* __restrict__ row_start,
                                                    const int2* __restrict__ epack,
                                                    const float* __restrict__ We,
                                                    const float* __restrict__ att,
                                                    const float* __restrict__ bias,
                                                    const float* __restrict__ bng,
                                                    const float* __restrict__ bnb,
                                                    const float* __restrict__ bnm,
                                                    const float* __restrict__ bnv,
                                                    const float* __restrict__ linW,
                                                    const float* __restrict__ linb,
                                                    float* __restrict__ out) {
    int n = (blockIdx.x * blockDim.x + threadIdx.x) >> 5;
    if (n >= NN) return;
    int q    = threadIdx.x & 31;
    int slot = q >> 3;              // edge slot 0..3 within the half-wave
    int c0   = (q & 7) << 2;        // 4 channels of 32

    const float L2E = 1.44269504f;
    const float4 xr = *(const float4*)(xlr + (size_t)n * 64 + 32 + c0);
    const float4 we = *(const float4*)(We + c0);
    const float4 at = *(const float4*)(att + c0);
    float4 a6, a4;
    a6.x = 0.6f * L2E * at.x; a4.x = 0.4f * L2E * at.x;
    a6.y = 0.6f * L2E * at.y; a4.y = 0.4f * L2E * at.y;
    a6.z = 0.6f * L2E * at.z; a4.z = 0.4f * L2E * at.z;
    a6.w = 0.6f * L2E * at.w; a4.w = 0.4f * L2E * at.w;

    int beg = row_start[n], end = row_start[n + 1];
    int lastE = end - 1;

    float mx = NEG_BIG, sm = 0.f;
    float4 ac = make_float4(0.f, 0.f, 0.f, 0.f);

    auto score4 = [&](float eav, const float4& xv) -> float {
        float m0 = xv.x + fmaf(eav, we.x, xr.x);
        float m1 = xv.y + fmaf(eav, we.y, xr.y);
        float m2 = xv.z + fmaf(eav, we.z, xr.z);
        float m3 = xv.w + fmaf(eav, we.w, xr.w);
        float p = fmaf(a6.x, m0, a4.x * fabsf(m0));
        p = fmaf(a6.y, m1, fmaf(a4.y, fabsf(m1), p));
        p = fmaf(a6.z, m2, fmaf(a4.z, fabsf(m2), p));
        p = fmaf(a6.w, m3, fmaf(a4.w, fabsf(m3), p));
        return dpp_add8(p);     // 32 ch = aligned 8-lane group
    };

    auto upd = [&](float p, const float4& xv) {
        float d = p - mx;
        if (__ballot(d > RESCALE_THR)) {
            float nm = fmaxf(mx, p);
            float sc = exp2f(mx - nm);
            float w  = exp2f(p - nm);
            sm = fmaf(sm, sc, w);
            ac.x = fmaf(ac.x, sc, w * xv.x); ac.y = fmaf(ac.y, sc, w * xv.y);
            ac.z = fmaf(ac.z, sc, w * xv.z); ac.w = fmaf(ac.w, sc, w * xv.w);
            mx = nm;
        } else {
            float w = exp2f(d);
            sm += w;
            ac.x = fmaf(w, xv.x, ac.x); ac.y = fmaf(w, xv.y, ac.y);
            ac.z = fmaf(w, xv.z, ac.z); ac.w = fmaf(w, xv.w, ac.w);
        }
    };

    int nE = end - beg;
    int last4 = beg + (nE & ~3);

    int2 pkn; float4 xvn;
    if (beg < last4) {
        pkn = epack[beg + slot];
        xvn = *(const float4*)(xlr + ((size_t)pkn.x << 6) + c0);
    }
    for (int j = beg; j < last4; ) {
        int2 pk = pkn; float4 xv = xvn;
        j += 4;
        if (j < last4) {
            pkn = epack[j + slot];
            xvn = *(const float4*)(xlr + ((size_t)pkn.x << 6) + c0);
        }
        float p = score4(__int_as_float(pk.y), xv);
        upd(p, xv);
    }
    if (last4 < end) {
        int je = last4 + slot;
        bool dead = je > lastE; if (dead) je = lastE;
        int2 pk = epack[je];
        float4 xv = *(const float4*)(xlr + ((size_t)pk.x << 6) + c0);
        float p = score4(__int_as_float(pk.y), xv);
        p = dead ? NEG_BIG : p;
        upd(p, xv);
    }

    // merge 4 slot-states within the half (shfl_xor 8 then 16; bit5 untouched)
#pragma unroll
    for (int off = 8; off <= 16; off <<= 1) {
        float  Mo  = __shfl_xor(mx, off);
        float  smo = __shfl_xor(sm, off);
        float4 aco;
        aco.x = __shfl_xor(ac.x, off); aco.y = __shfl_xor(ac.y, off);
        aco.z = __shfl_xor(ac.z, off); aco.w = __shfl_xor(ac.w, off);
        float Mn = fmaxf(mx, Mo);
        float ss = exp2f(mx - Mn), so = exp2f(Mo - Mn);
        sm = fmaf(sm, ss, smo * so);
        ac.x = fmaf(ac.x, ss, aco.x * so); ac.y = fmaf(ac.y, ss, aco.y * so);
        ac.z = fmaf(ac.z, ss, aco.z * so); ac.w = fmaf(ac.w, ss, aco.w * so);
        mx = Mn;
    }

    float inv = 1.f / (sm + 1e-16f);
    const float4 b4 = *(const float4*)(bias + c0);
    const float4 g4 = *(const float4*)(bng + c0);
    const float4 q4 = *(const float4*)(bnb + c0);
    const float4 m4 = *(const float4*)(bnm + c0);
    const float4 v4 = *(const float4*)(bnv + c0);
    float4 y;
    y.x = fmaxf(fmaf(ac.x, inv, b4.x), 0.f);
    y.y = fmaxf(fmaf(ac.y, inv, b4.y), 0.f);
    y.z = fmaxf(fmaf(ac.z, inv, b4.z), 0.f);
    y.w = fmaxf(fmaf(ac.w, inv, b4.w), 0.f);
    y.x = (y.x - m4.x) * rsqrtf(v4.x + EPS) * g4.x + q4.x;
    y.y = (y.y - m4.y) * rsqrtf(v4.y + EPS) * g4.y + q4.y;
    y.z = (y.z - m4.z) * rsqrtf(v4.z + EPS) * g4.z + q4.z;
    y.w = (y.w - m4.w) * rsqrtf(v4.w + EPS) * g4.w + q4.w;

    // fused linear: t[k] = sum_c y_c * linW[c][k]; per-lane 4 rows of linW
    const float4 w0 = *(const float4*)(linW + (c0 + 0) * 4);
    const float4 w1 = *(const float4*)(linW + (c0 + 1) * 4);
    const float4 w2 = *(const float4*)(linW + (c0 + 2) * 4);
    const float4 w3 = *(const float4*)(linW + (c0 + 3) * 4);
    float4 t;
    t.x = fmaf(y.x, w0.x, fmaf(y.y, w1.x, fmaf(y.z, w2.x, y.w * w3.x)));
    t.y = fmaf(y.x, w0.y, fmaf(y.y, w1.y, fmaf(y.z, w2.y, y.w * w3.y)));
    t.z = fmaf(y.x, w0.z, fmaf(y.y, w1.z, fmaf(y.z, w2.z, y.w * w3.z)));
    t.w = fmaf(y.x, w0.w, fmaf(y.y, w1.w, fmaf(y.z, w2.w, y.w * w3.w)));
    t.x = dpp_add8(t.x); t.y = dpp_add8(t.y);
    t.z = dpp_add8(t.z); t.w = dpp_add8(t.w);

    if (q == 0) {
        const float4 lb = *(const float4*)linb;
        float4 o;
        o.x = t.x + lb.x; o.y = t.y + lb.y; o.z = t.z + lb.z; o.w = t.w + lb.w;
        *(float4*)(out + (size_t)n * 4) = o;
    }
}

// ---------------------------------------------------------------------------
extern "C" void kernel_launch(void* const* d_in, const int* in_sizes, int n_in,
                              void* d_out, int out_size, void* d_ws, size_t ws_size,
                              hipStream_t stream) {
    const float* x      = (const float*)d_in[0];
    const int*   ei     = (const int*)d_in[1];
    const float* ea     = (const float*)d_in[2];
    const float* l1_Wl  = (const float*)d_in[3];
    const float* l1_Wr  = (const float*)d_in[4];
    const float* l1_We  = (const float*)d_in[5];
    const float* l1_att = (const float*)d_in[6];
    const float* l1_b   = (const float*)d_in[7];
    const float* mid_Wl = (const float*)d_in[8];
    const float* mid_Wr = (const float*)d_in[9];
    const float* mid_We = (const float*)d_in[10];
    const float* mid_att= (const float*)d_in[11];
    const float* mid_b  = (const float*)d_in[12];
    const float* l10_Wl = (const float*)d_in[13];
    const float* l10_Wr = (const float*)d_in[14];
    const float* l10_We = (const float*)d_in[15];
    const float* l10_att= (const float*)d_in[16];
    const float* l10_b  = (const float*)d_in[17];
    const float* bn_g   = (const float*)d_in[18];
    const float* bn_b   = (const float*)d_in[19];
    const float* bn_m   = (const float*)d_in[20];
    const float* bn_v   = (const float*)d_in[21];
    const float* bn10_g = (const float*)d_in[22];
    const float* bn10_b = (const float*)d_in[23];
    const float* bn10_m = (const float*)d_in[24];
    const float* bn10_v = (const float*)d_in[25];
    const float* lin_W  = (const float*)d_in[26];
    const float* lin_b  = (const float*)d_in[27];

    char* ws = (char*)d_ws;
    auto take = [&](size_t bytes) { char* p = ws; ws += (bytes + 255) & ~size_t(255); return p; };
    int*   row_start  = (int*)  take(sizeof(int) * (NN + 1));
    int*   cursor     = (int*)  take(sizeof(int) * NN);
    int*   part       = (int*)  take(sizeof(int) * 256);
    int2*  epack      = (int2*) take(sizeof(int2) * EE);
    float* xlr        = (float*)take(sizeof(float) * (size_t)NN * 256);
    u16*   Ahi        = (u16*)  take(sizeof(u16) * (size_t)NN * 128);
    u16*   Alo        = (u16*)  take(sizeof(u16) * (size_t)NN * 128);
    u16*   Wthi       = (u16*)  take(sizeof(u16) * 9 * 256 * 128);
    u16*   Wtlo       = (u16*)  take(sizeof(u16) * 9 * 256 * 128);
    u16*   Wt10hi     = (u16*)  take(sizeof(u16) * 64 * 128);
    u16*   Wt10lo     = (u16*)  take(sizeof(u16) * 64 * 128);

    // --- CSR build ---
    hipMemsetAsync(cursor, 0, sizeof(int) * NN, stream);
    hist_kernel<<<EE / 256, 256, 0, stream>>>(ei + EE, cursor);
    scan_part<<<256, 256, 0, stream>>>(cursor, part);
    scan_final<<<256, 256, 0, stream>>>(cursor, part, row_start);
    scatter_kernel<<<EE / 256, 256, 0, stream>>>(ei, ea, cursor, epack);

    // --- one-time conversions (single fused dispatch) ---
    prep_all<<<(PREP_TOTAL + 255) / 256, 256, 0, stream>>>(
        x, l1_Wl, l1_Wr, mid_Wl, mid_Wr, l10_Wl, l10_Wr,
        Ahi, Alo, Wthi, Wtlo, Wt10hi, Wt10lo);

    const int GBM = (NN + 63) / 64;                 // 782 row-blocks

    // --- layer 1 ---
    gemm_mfma<<<GBM, 512, 0, stream>>>(Ahi, Alo, Wthi, Wtlo, xlr);
    node_agg_128<<<(NN * 64) / 256, 256, 0, stream>>>(
        xlr, row_start, epack, l1_We, l1_att, l1_b,
        bn_g, bn_b, bn_m, bn_v, Ahi, Alo);

    // --- layers 2-9 ---
    for (int i = 0; i < 8; ++i) {
        gemm_mfma<<<GBM, 512, 0, stream>>>(Ahi, Alo,
                                           Wthi + (size_t)(i + 1) * 32768,
                                           Wtlo + (size_t)(i + 1) * 32768, xlr);
        node_agg_128<<<(NN * 64) / 256, 256, 0, stream>>>(
            xlr, row_start, epack,
            mid_We + (size_t)i * 128, mid_att + (size_t)i * 128, mid_b + (size_t)i * 128,
            bn_g + (size_t)(i + 1) * 128, bn_b + (size_t)(i + 1) * 128,
            bn_m + (size_t)(i + 1) * 128, bn_v + (size_t)(i + 1) * 128,
            Ahi, Alo);
    }

    // --- layer 10: MFMA GEMM -> xlr[N][64], then aggregate+linear ---
    gemm_mfma_l10<<<GBM, 256, 0, stream>>>(Ahi, Alo, Wt10hi, Wt10lo, xlr);
    node_agg_l10<<<(NN * 32 + 255) / 256, 256, 0, stream>>>(
        xlr, row_start, epack, l10_We, l10_att, l10_b,
        bn10_g, bn10_b, bn10_m, bn10_v, lin_W, lin_b, (float*)d_out);
}

// Round 13
// 1046.388 us; speedup vs baseline: 1.0073x; 1.0073x over previous
//
#include <hip/hip_runtime.h>
#include <math.h>

#define NN 50000
#define EE 800000
#define EPS 1e-5f
#define SCAN_CH 196   // ceil(NN/256)

#define NEG_BIG (-1e30f)
#define RESCALE_THR 4.0f

#define LO_SCALE 2048.0f       // 2^11 exponent shift for the f16 lo plane
#define LO_INV   (1.0f/2048.0f)

typedef unsigned short u16;
typedef _Float16 f16x8 __attribute__((ext_vector_type(8)));
typedef float f32x4 __attribute__((ext_vector_type(4)));

__device__ __forceinline__ u16 f2h(float f) {
    _Float16 h = (_Float16)f;               // v_cvt_f16_f32, RNE
    return __builtin_bit_cast(u16, h);
}
__device__ __forceinline__ float h2f(u16 u) {
    return (float)__builtin_bit_cast(_Float16, u);
}

__device__ __forceinline__ float dpp_add8(float x) {
    int t;
    t = __builtin_amdgcn_update_dpp(0, __float_as_int(x), 0xB1, 0xf, 0xf, true);
    x += __int_as_float(t);
    t = __builtin_amdgcn_update_dpp(0, __float_as_int(x), 0x4E, 0xf, 0xf, true);
    x += __int_as_float(t);
    t = __builtin_amdgcn_update_dpp(0, __float_as_int(x), 0x141, 0xf, 0xf, true);
    x += __int_as_float(t);
    return x;
}

// ---------------------------------------------------------------------------
// CSR build: histogram -> scan (partials; final scan inlined) -> scatter
// ---------------------------------------------------------------------------
__global__ void hist_kernel(const int* __restrict__ dst, int* cnt) {
    int e = blockIdx.x * blockDim.x + threadIdx.x;
    if (e < EE) atomicAdd(&cnt[dst[e]], 1);
}

__global__ void scan_part(const int* __restrict__ cnt, int* __restrict__ part) {
    __shared__ int red[256];
    int b = blockIdx.x, t = threadIdx.x;
    int i = b * SCAN_CH + t;
    int v = (t < SCAN_CH && i < NN) ? cnt[i] : 0;
    red[t] = v;
    __syncthreads();
#pragma unroll
    for (int s = 128; s; s >>= 1) {
        if (t < s) red[t] += red[t + s];
        __syncthreads();
    }
    if (t == 0) part[b] = red[0];
}

// 256 blocks: inline full scan of 256 partials (redundant per block, cheap)
// + in-block inclusive scan -> row_start & cursor.
__global__ void scan_final(int* __restrict__ cntcur, const int* __restrict__ part,
                           int* __restrict__ row_start) {
    __shared__ int pbuf[2][256];
    __shared__ int buf[2][256];
    int b = blockIdx.x, t = threadIdx.x;

    int pv = part[t];
    int pp = 0;
    pbuf[0][t] = pv;
    __syncthreads();
#pragma unroll
    for (int off = 1; off < 256; off <<= 1) {
        pbuf[pp ^ 1][t] = pbuf[pp][t] + ((t >= off) ? pbuf[pp][t - off] : 0);
        __syncthreads();
        pp ^= 1;
    }
    int base = (b == 0) ? 0 : pbuf[pp][b - 1];   // exclusive offset of block b

    int i = b * SCAN_CH + t;
    int v = (t < SCAN_CH && i < NN) ? cntcur[i] : 0;
    int p = 0;
    buf[0][t] = v;
    __syncthreads();
#pragma unroll
    for (int off = 1; off < 256; off <<= 1) {
        buf[p ^ 1][t] = buf[p][t] + ((t >= off) ? buf[p][t - off] : 0);
        __syncthreads();
        p ^= 1;
    }
    if (t < SCAN_CH && i < NN) {
        int pos = base + buf[p][t] - v;      // exclusive
        row_start[i] = pos;
        cntcur[i] = pos;                     // scatter cursor
    }
    if (b == 0 && t == 0) row_start[NN] = EE;
}

__global__ void scatter_kernel(const int* __restrict__ ei, const float* __restrict__ ea,
                               int* cursor, int2* __restrict__ edge_pack) {
    int e = blockIdx.x * blockDim.x + threadIdx.x;
    if (e < EE) {
        int d = ei[EE + e];
        int pos = atomicAdd(&cursor[d], 1);
        edge_pack[pos] = make_int2(ei[e], __float_as_int(ea[e]));
    }
}

// ---------------------------------------------------------------------------
// One-time prep, fused into a single dispatch.
// ---------------------------------------------------------------------------
#define SPLIT_N4   (NN * 128 / 4)        // 1,600,000
#define CONVW_N    (9 * 256 * 128)       // 294,912
#define CONVW10_N  (64 * 128)            // 8,192
#define PREP_TOTAL (SPLIT_N4 + CONVW_N + CONVW10_N)

__global__ void prep_all(const float* __restrict__ x,
                         const float* __restrict__ l1Wl, const float* __restrict__ l1Wr,
                         const float* __restrict__ midWl, const float* __restrict__ midWr,
                         const float* __restrict__ l10Wl, const float* __restrict__ l10Wr,
                         u16* __restrict__ Ahi, u16* __restrict__ Alo,
                         u16* __restrict__ Wh, u16* __restrict__ Wlo,
                         u16* __restrict__ W10h, u16* __restrict__ W10lo) {
    int tid = blockIdx.x * 256 + threadIdx.x;
    if (tid < SPLIT_N4) {
        float4 v = ((const float4*)x)[tid];
        ushort4 h, l;
        h.x = f2h(v.x); l.x = f2h((v.x - h2f(h.x)) * LO_SCALE);
        h.y = f2h(v.y); l.y = f2h((v.y - h2f(h.y)) * LO_SCALE);
        h.z = f2h(v.z); l.z = f2h((v.z - h2f(h.z)) * LO_SCALE);
        h.w = f2h(v.w); l.w = f2h((v.w - h2f(h.w)) * LO_SCALE);
        ((ushort4*)Ahi)[tid] = h;
        ((ushort4*)Alo)[tid] = l;
    } else if (tid < SPLIT_N4 + CONVW_N) {
        int c = tid - SPLIT_N4;
        int L = c >> 15;
        int rem = c & 32767;
        int n = rem >> 7, k = rem & 127;
        const float* WL;
        const float* WR;
        if (L == 0) { WL = l1Wl; WR = l1Wr; }
        else {
            WL = midWl + (size_t)(L - 1) * 16384;
            WR = midWr + (size_t)(L - 1) * 16384;
        }
        float w = (n < 128) ? WL[k * 128 + n] : WR[k * 128 + (n - 128)];
        u16 h = f2h(w);
        Wh[c] = h;
        Wlo[c] = f2h((w - h2f(h)) * LO_SCALE);
    } else if (tid < PREP_TOTAL) {
        int c = tid - SPLIT_N4 - CONVW_N;
        int n = c >> 7, k = c & 127;
        float w = (n < 32) ? l10Wl[k * 32 + n] : l10Wr[k * 32 + (n - 32)];
        u16 h = f2h(w);
        W10h[c] = h;
        W10lo[c] = f2h((w - h2f(h)) * LO_SCALE);
    }
}

// ---------------------------------------------------------------------------
// MFMA f16 split GEMM (round-11 proven, frozen): LDS-shared A.
// ---------------------------------------------------------------------------
#define ASTRIDE 136   // u16 units: 128 + 8 pad

__global__ __launch_bounds__(512) void gemm_mfma(const u16* __restrict__ Ah,
                                                 const u16* __restrict__ Al,
                                                 const u16* __restrict__ Bh,
                                                 const u16* __restrict__ Bl,
                                                 float* __restrict__ C) {
    __shared__ u16 Ahs[64 * ASTRIDE];
    __shared__ u16 Als[64 * ASTRIDE];

    int t    = threadIdx.x;
    int w    = t >> 6;               // wave 0..7
    int lane = t & 63;
    int lr = lane & 15;
    int kg = lane >> 4;
    int rowbase = blockIdx.x * 64;

    int colbase = w * 32;            // 0..224 within Wt[256]
    int y    = colbase >> 7;         // output plane
    int colb = colbase & 127;        // col within plane
    f16x8 bh[2][4], bl[2][4];
#pragma unroll
    for (int ct = 0; ct < 2; ++ct) {
        size_t boff = (size_t)(colbase + ct * 16 + lr) * 128 + (size_t)(kg * 8);
#pragma unroll
        for (int ks = 0; ks < 4; ++ks) {
            bh[ct][ks] = *(const f16x8*)(Bh + boff + ks * 32);
            bl[ct][ks] = *(const f16x8*)(Bl + boff + ks * 32);
        }
    }

#pragma unroll
    for (int i = 0; i < 2; ++i) {
        int c = t + i * 512;                  // 0..1023
        int row  = c >> 4;                    // 0..63 (16 chunks per row)
        int colu = (c & 15) * 8;              // u16 offset within row
        int grow = rowbase + row; if (grow >= NN) grow = NN - 1;
        size_t go = (size_t)grow * 128 + colu;
        *(f16x8*)(Ahs + row * ASTRIDE + colu) = *(const f16x8*)(Ah + go);
        *(f16x8*)(Als + row * ASTRIDE + colu) = *(const f16x8*)(Al + go);
    }
    __syncthreads();

    float* Cp = C + (size_t)y * ((size_t)NN * 128);

#pragma unroll
    for (int rt = 0; rt < 4; ++rt) {
        int abase = (rt * 16 + lr) * ASTRIDE + kg * 8;
        f16x8 ah[4], al[4];
#pragma unroll
        for (int ks = 0; ks < 4; ++ks) {
            ah[ks] = *(const f16x8*)(Ahs + abase + ks * 32);
            al[ks] = *(const f16x8*)(Als + abase + ks * 32);
        }

        f32x4 aH[2], aL[2];
#pragma unroll
        for (int ct = 0; ct < 2; ++ct) {
            aH[ct] = (f32x4){0.f, 0.f, 0.f, 0.f};
            aL[ct] = (f32x4){0.f, 0.f, 0.f, 0.f};
        }
#pragma unroll
        for (int ks = 0; ks < 4; ++ks) {
#pragma unroll
            for (int ct = 0; ct < 2; ++ct) {
                aH[ct] = __builtin_amdgcn_mfma_f32_16x16x32_f16(ah[ks], bh[ct][ks], aH[ct], 0, 0, 0);
                aL[ct] = __builtin_amdgcn_mfma_f32_16x16x32_f16(al[ks], bh[ct][ks], aL[ct], 0, 0, 0);
                aL[ct] = __builtin_amdgcn_mfma_f32_16x16x32_f16(ah[ks], bl[ct][ks], aL[ct], 0, 0, 0);
            }
        }

        int crow0 = rowbase + rt * 16 + kg * 4;
#pragma unroll
        for (int ct = 0; ct < 2; ++ct) {
            float* cp = Cp + (size_t)crow0 * 128 + colb + ct * 16 + lr;
#pragma unroll
            for (int r = 0; r < 4; ++r) {
                if (crow0 + r < NN)
                    cp[(size_t)r * 128] = fmaf(aL[ct][r], LO_INV, aH[ct][r]);
            }
        }
    }
}

// ---------------------------------------------------------------------------
// Layer-10 GEMM via MFMA (64 cols): C[N][64] fp32 = A[N][128] @ Wt10^T.
// ---------------------------------------------------------------------------
__global__ __launch_bounds__(256) void gemm_mfma_l10(const u16* __restrict__ Ah,
                                                     const u16* __restrict__ Al,
                                                     const u16* __restrict__ Bh,
                                                     const u16* __restrict__ Bl,
                                                     float* __restrict__ C) {
    int w    = threadIdx.x >> 6;
    int lane = threadIdx.x & 63;
    int lr = lane & 15;
    int kg = lane >> 4;
    int rowbase = blockIdx.x * 64;
    int colb = w * 16;                      // 4 waves cover 64 cols

    f16x8 bh[4], bl[4];
    {
        size_t boff = (size_t)(colb + lr) * 128 + (size_t)(kg * 8);
#pragma unroll
        for (int ks = 0; ks < 4; ++ks) {
            bh[ks] = *(const f16x8*)(Bh + boff + ks * 32);
            bl[ks] = *(const f16x8*)(Bl + boff + ks * 32);
        }
    }

    auto aoff_of = [&](int rt) {
        int arow = rowbase + rt * 16 + lr;
        if (arow >= NN) arow = NN - 1;
        return (size_t)arow * 128 + (size_t)(kg * 8);
    };
    f16x8 ahc[4], alc[4], ahn[4], aln[4];
    {
        size_t ao = aoff_of(0);
#pragma unroll
        for (int ks = 0; ks < 4; ++ks) {
            ahc[ks] = *(const f16x8*)(Ah + ao + ks * 32);
            alc[ks] = *(const f16x8*)(Al + ao + ks * 32);
        }
    }

#pragma unroll
    for (int rt = 0; rt < 4; ++rt) {
        if (rt < 3) {
            size_t ao = aoff_of(rt + 1);
#pragma unroll
            for (int ks = 0; ks < 4; ++ks) {
                ahn[ks] = *(const f16x8*)(Ah + ao + ks * 32);
                aln[ks] = *(const f16x8*)(Al + ao + ks * 32);
            }
        }

        f32x4 aH = (f32x4){0.f, 0.f, 0.f, 0.f};
        f32x4 aL = (f32x4){0.f, 0.f, 0.f, 0.f};
#pragma unroll
        for (int ks = 0; ks < 4; ++ks) {
            aH = __builtin_amdgcn_mfma_f32_16x16x32_f16(ahc[ks], bh[ks], aH, 0, 0, 0);
            aL = __builtin_amdgcn_mfma_f32_16x16x32_f16(alc[ks], bh[ks], aL, 0, 0, 0);
            aL = __builtin_amdgcn_mfma_f32_16x16x32_f16(ahc[ks], bl[ks], aL, 0, 0, 0);
        }

        int crow0 = rowbase + rt * 16 + kg * 4;
        float* cp = C + (size_t)crow0 * 64 + colb + lr;
#pragma unroll
        for (int r = 0; r < 4; ++r) {
            if (crow0 + r < NN)
                cp[(size_t)r * 64] = fmaf(aL[r], LO_INV, aH[r]);
        }

        if (rt < 3) {
#pragma unroll
            for (int ks = 0; ks < 4; ++ks) { ahc[ks] = ahn[ks]; alc[ks] = aln[ks]; }
        }
    }
}

// ---------------------------------------------------------------------------
// Node kernel layers 1-9: EXACT round-11 proven configuration (VGPR 32,
// plain loop, per-state ballot). One wave per node, half-wave per edge,
// 4 ch/lane, DPP head reduce, defer-max online softmax.
// ---------------------------------------------------------------------------
__global__ __launch_bounds__(256) void node_agg_128(const float* __restrict__ xlr,
                                                    const int* __restrict__ row_start,
                                                    const int2* __restrict__ epack,
                                                    const float* __restrict__ We,
                                                    const float* __restrict__ att,
                                                    const float* __restrict__ bias,
                                                    const float* __restrict__ bng,
                                                    const float* __restrict__ bnb,
                                                    const float* __restrict__ bnm,
                                                    const float* __restrict__ bnv,
                                                    u16* __restrict__ ahi,
                                                    u16* __restrict__ alo) {
    int node = (blockIdx.x * blockDim.x + threadIdx.x) >> 6;
    int lane = threadIdx.x & 63;
    if (node >= NN) return;
    int half = lane >> 5;
    int c0   = (lane & 31) << 2;

    const float* xlp = xlr;                           // xl plane [N][128]
    const float* xrp = xlr + (size_t)NN * 128;        // xr plane [N][128]

    const float L2E = 1.44269504f;
    const float4 xr4 = *(const float4*)(xrp + (size_t)node * 128 + c0);
    const float4 we4 = *(const float4*)(We + c0);
    const float4 at4 = *(const float4*)(att + c0);
    float4 a6, a4;
    a6.x = 0.6f * L2E * at4.x; a4.x = 0.4f * L2E * at4.x;
    a6.y = 0.6f * L2E * at4.y; a4.y = 0.4f * L2E * at4.y;
    a6.z = 0.6f * L2E * at4.z; a4.z = 0.4f * L2E * at4.z;
    a6.w = 0.6f * L2E * at4.w; a4.w = 0.4f * L2E * at4.w;

    int beg = row_start[node], end = row_start[node + 1];
    int lastE = end - 1;

    float mx0 = NEG_BIG, sm0 = 0.f;
    float mx1 = NEG_BIG, sm1 = 0.f;
    float4 ac0 = make_float4(0.f, 0.f, 0.f, 0.f);
    float4 ac1 = make_float4(0.f, 0.f, 0.f, 0.f);

    auto score = [&](float eav, const float4& xv) -> float {
        float m0 = xv.x + fmaf(eav, we4.x, xr4.x);
        float m1 = xv.y + fmaf(eav, we4.y, xr4.y);
        float m2 = xv.z + fmaf(eav, we4.z, xr4.z);
        float m3 = xv.w + fmaf(eav, we4.w, xr4.w);
        float p = fmaf(a6.x, m0, a4.x * fabsf(m0));
        p = fmaf(a6.y, m1, fmaf(a4.y, fabsf(m1), p));
        p = fmaf(a6.z, m2, fmaf(a4.z, fabsf(m2), p));
        p = fmaf(a6.w, m3, fmaf(a4.w, fabsf(m3), p));
        return dpp_add8(p);
    };

    auto upd = [&](float& mx, float& sm, float4& ac, float p, const float4& xv) {
        float d = p - mx;
        if (__ballot(d > RESCALE_THR)) {
            float nm = fmaxf(mx, p);
            float sc = exp2f(mx - nm);
            float w  = exp2f(p - nm);
            sm = fmaf(sm, sc, w);
            ac.x = fmaf(ac.x, sc, w * xv.x);
            ac.y = fmaf(ac.y, sc, w * xv.y);
            ac.z = fmaf(ac.z, sc, w * xv.z);
            ac.w = fmaf(ac.w, sc, w * xv.w);
            mx = nm;
        } else {
            float w = exp2f(d);
            sm += w;
            ac.x = fmaf(w, xv.x, ac.x);
            ac.y = fmaf(w, xv.y, ac.y);
            ac.z = fmaf(w, xv.z, ac.z);
            ac.w = fmaf(w, xv.w, ac.w);
        }
    };

    int j = beg;
    for (; j + 3 < end; j += 4) {
        int2 pkA = epack[j + half];
        int2 pkB = epack[j + 2 + half];
        float4 xA = *(const float4*)(xlp + ((size_t)pkA.x << 7) + c0);
        float4 xB = *(const float4*)(xlp + ((size_t)pkB.x << 7) + c0);
        float pA = score(__int_as_float(pkA.y), xA);
        float pB = score(__int_as_float(pkB.y), xB);
        upd(mx0, sm0, ac0, pA, xA);
        upd(mx1, sm1, ac1, pB, xB);
    }
    if (j < end) {   // tail: 1..3 real edges; dead slots forced NEG_BIG
        int jeA = j + half;       bool dA = jeA > lastE; if (dA) jeA = lastE;
        int jeB = j + 2 + half;   bool dB = jeB > lastE; if (dB) jeB = lastE;
        int2 pkA = epack[jeA];
        int2 pkB = epack[jeB];
        float4 xA = *(const float4*)(xlp + ((size_t)pkA.x << 7) + c0);
        float4 xB = *(const float4*)(xlp + ((size_t)pkB.x << 7) + c0);
        float pA = score(__int_as_float(pkA.y), xA);
        float pB = score(__int_as_float(pkB.y), xB);
        pA = dA ? NEG_BIG : pA;
        pB = dB ? NEG_BIG : pB;
        upd(mx0, sm0, ac0, pA, xA);
        upd(mx1, sm1, ac1, pB, xB);
    }

    // merge the 2 states in-lane
    float Mx = fmaxf(mx0, mx1);
    float s0 = exp2f(mx0 - Mx), s1 = exp2f(mx1 - Mx);
    float sm = fmaf(sm0, s0, sm1 * s1);
    float4 ac;
    ac.x = fmaf(ac0.x, s0, ac1.x * s1);
    ac.y = fmaf(ac0.y, s0, ac1.y * s1);
    ac.z = fmaf(ac0.z, s0, ac1.z * s1);
    ac.w = fmaf(ac0.w, s0, ac1.w * s1);

    // merge across halves (lanes l and l+32 hold the same channels)
    float  Mo  = __shfl_xor(Mx, 32);
    float  smo = __shfl_xor(sm, 32);
    float4 aco;
    aco.x = __shfl_xor(ac.x, 32);
    aco.y = __shfl_xor(ac.y, 32);
    aco.z = __shfl_xor(ac.z, 32);
    aco.w = __shfl_xor(ac.w, 32);
    float Mn = fmaxf(Mx, Mo);
    float ss = exp2f(Mx - Mn), so = exp2f(Mo - Mn);
    sm   = fmaf(sm, ss, smo * so);
    ac.x = fmaf(ac.x, ss, aco.x * so);
    ac.y = fmaf(ac.y, ss, aco.y * so);
    ac.z = fmaf(ac.z, ss, aco.z * so);
    ac.w = fmaf(ac.w, ss, aco.w * so);

    if (half == 0) {
        float inv = 1.f / (sm + 1e-16f);
        const float4 b4  = *(const float4*)(bias + c0);
        const float4 g4  = *(const float4*)(bng + c0);
        const float4 bb4 = *(const float4*)(bnb + c0);
        const float4 m4  = *(const float4*)(bnm + c0);
        const float4 v4  = *(const float4*)(bnv + c0);
        float4 y;
        y.x = fmaxf(fmaf(ac.x, inv, b4.x), 0.f);
        y.y = fmaxf(fmaf(ac.y, inv, b4.y), 0.f);
        y.z = fmaxf(fmaf(ac.z, inv, b4.z), 0.f);
        y.w = fmaxf(fmaf(ac.w, inv, b4.w), 0.f);
        y.x = (y.x - m4.x) * rsqrtf(v4.x + EPS) * g4.x + bb4.x;
        y.y = (y.y - m4.y) * rsqrtf(v4.y + EPS) * g4.y + bb4.y;
        y.z = (y.z - m4.z) * rsqrtf(v4.z + EPS) * g4.z + bb4.z;
        y.w = (y.w - m4.w) * rsqrtf(v4.w + EPS) * g4.w + bb4.w;

        ushort4 hh, ll;
        hh.x = f2h(y.x); ll.x = f2h((y.x - h2f(hh.x)) * LO_SCALE);
        hh.y = f2h(y.y); ll.y = f2h((y.y - h2f(hh.y)) * LO_SCALE);
        hh.z = f2h(y.z); ll.z = f2h((y.z - h2f(hh.z)) * LO_SCALE);
        hh.w = f2h(y.w); ll.w = f2h((y.w - h2f(hh.w)) * LO_SCALE);
        *(ushort4*)(ahi + (size_t)node * 128 + c0) = hh;
        *(ushort4*)(alo + (size_t)node * 128 + c0) = ll;
    }
}

// ---------------------------------------------------------------------------
// Layer 10: half-wave per node, 8 lanes/edge x 4 ch/lane, 4 edge slots,
// float4 gathers, dpp_add8 head reduce, defer-max, fused linear.
// ---------------------------------------------------------------------------
__global__ __launch_bounds__(256) void node_agg_l10(const float* __restrict__ xlr,
                                                    const int* __restrict__ row_start,
                                                    const int2* __restrict__ epack,
                                                    const float* __restrict__ We,
                                                    const float* __restrict__ att,
                                                    const float* __restrict__ bias,
                                                    const float* __restrict__ bng,
                                                    const float* __restrict__ bnb,
                                                    const float* __restrict__ bnm,
                                                    const float* __restrict__ bnv,
                                                    const float* __restrict__ linW,
                                                    const float* __restrict__ linb,
                                                    float* __restrict__ out) {
    int n = (blockIdx.x * blockDim.x + threadIdx.x) >> 5;
    if (n >= NN) return;
    int q    = threadIdx.x & 31;
    int slot = q >> 3;              // edge slot 0..3 within the half-wave
    int c0   = (q & 7) << 2;        // 4 channels of 32

    const float L2E = 1.44269504f;
    const float4 xr = *(const float4*)(xlr + (size_t)n * 64 + 32 + c0);
    const float4 we = *(const float4*)(We + c0);
    const float4 at = *(const float4*)(att + c0);
    float4 a6, a4;
    a6.x = 0.6f * L2E * at.x; a4.x = 0.4f * L2E * at.x;
    a6.y = 0.6f * L2E * at.y; a4.y = 0.4f * L2E * at.y;
    a6.z = 0.6f * L2E * at.z; a4.z = 0.4f * L2E * at.z;
    a6.w = 0.6f * L2E * at.w; a4.w = 0.4f * L2E * at.w;

    int beg = row_start[n], end = row_start[n + 1];
    int lastE = end - 1;

    float mx = NEG_BIG, sm = 0.f;
    float4 ac = make_float4(0.f, 0.f, 0.f, 0.f);

    auto score4 = [&](float eav, const float4& xv) -> float {
        float m0 = xv.x + fmaf(eav, we.x, xr.x);
        float m1 = xv.y + fmaf(eav, we.y, xr.y);
        float m2 = xv.z + fmaf(eav, we.z, xr.z);
        float m3 = xv.w + fmaf(eav, we.w, xr.w);
        float p = fmaf(a6.x, m0, a4.x * fabsf(m0));
        p = fmaf(a6.y, m1, fmaf(a4.y, fabsf(m1), p));
        p = fmaf(a6.z, m2, fmaf(a4.z, fabsf(m2), p));
        p = fmaf(a6.w, m3, fmaf(a4.w, fabsf(m3), p));
        return dpp_add8(p);     // 32 ch = aligned 8-lane group
    };

    auto upd = [&](float p, const float4& xv) {
        float d = p - mx;
        if (__ballot(d > RESCALE_THR)) {
            float nm = fmaxf(mx, p);
            float sc = exp2f(mx - nm);
            float w  = exp2f(p - nm);
            sm = fmaf(sm, sc, w);
            ac.x = fmaf(ac.x, sc, w * xv.x); ac.y = fmaf(ac.y, sc, w * xv.y);
            ac.z = fmaf(ac.z, sc, w * xv.z); ac.w = fmaf(ac.w, sc, w * xv.w);
            mx = nm;
        } else {
            float w = exp2f(d);
            sm += w;
            ac.x = fmaf(w, xv.x, ac.x); ac.y = fmaf(w, xv.y, ac.y);
            ac.z = fmaf(w, xv.z, ac.z); ac.w = fmaf(w, xv.w, ac.w);
        }
    };

    int nE = end - beg;
    int last4 = beg + (nE & ~3);

    int2 pkn; float4 xvn;
    if (beg < last4) {
        pkn = epack[beg + slot];
        xvn = *(const float4*)(xlr + ((size_t)pkn.x << 6) + c0);
    }
    for (int j = beg; j < last4; ) {
        int2 pk = pkn; float4 xv = xvn;
        j += 4;
        if (j < last4) {
            pkn = epack[j + slot];
            xvn = *(const float4*)(xlr + ((size_t)pkn.x << 6) + c0);
        }
        float p = score4(__int_as_float(pk.y), xv);
        upd(p, xv);
    }
    if (last4 < end) {
        int je = last4 + slot;
        bool dead = je > lastE; if (dead) je = lastE;
        int2 pk = epack[je];
        float4 xv = *(const float4*)(xlr + ((size_t)pk.x << 6) + c0);
        float p = score4(__int_as_float(pk.y), xv);
        p = dead ? NEG_BIG : p;
        upd(p, xv);
    }

    // merge 4 slot-states within the half (shfl_xor 8 then 16; bit5 untouched)
#pragma unroll
    for (int off = 8; off <= 16; off <<= 1) {
        float  Mo  = __shfl_xor(mx, off);
        float  smo = __shfl_xor(sm, off);
        float4 aco;
        aco.x = __shfl_xor(ac.x, off); aco.y = __shfl_xor(ac.y, off);
        aco.z = __shfl_xor(ac.z, off); aco.w = __shfl_xor(ac.w, off);
        float Mn = fmaxf(mx, Mo);
        float ss = exp2f(mx - Mn), so = exp2f(Mo - Mn);
        sm = fmaf(sm, ss, smo * so);
        ac.x = fmaf(ac.x, ss, aco.x * so); ac.y = fmaf(ac.y, ss, aco.y * so);
        ac.z = fmaf(ac.z, ss, aco.z * so); ac.w = fmaf(ac.w, ss, aco.w * so);
        mx = Mn;
    }

    float inv = 1.f / (sm + 1e-16f);
    const float4 b4 = *(const float4*)(bias + c0);
    const float4 g4 = *(const float4*)(bng + c0);
    const float4 q4 = *(const float4*)(bnb + c0);
    const float4 m4 = *(const float4*)(bnm + c0);
    const float4 v4 = *(const float4*)(bnv + c0);
    float4 y;
    y.x = fmaxf(fmaf(ac.x, inv, b4.x), 0.f);
    y.y = fmaxf(fmaf(ac.y, inv, b4.y), 0.f);
    y.z = fmaxf(fmaf(ac.z, inv, b4.z), 0.f);
    y.w = fmaxf(fmaf(ac.w, inv, b4.w), 0.f);
    y.x = (y.x - m4.x) * rsqrtf(v4.x + EPS) * g4.x + q4.x;
    y.y = (y.y - m4.y) * rsqrtf(v4.y + EPS) * g4.y + q4.y;
    y.z = (y.z - m4.z) * rsqrtf(v4.z + EPS) * g4.z + q4.z;
    y.w = (y.w - m4.w) * rsqrtf(v4.w + EPS) * g4.w + q4.w;

    // fused linear: t[k] = sum_c y_c * linW[c][k]; per-lane 4 rows of linW
    const float4 w0 = *(const float4*)(linW + (c0 + 0) * 4);
    const float4 w1 = *(const float4*)(linW + (c0 + 1) * 4);
    const float4 w2 = *(const float4*)(linW + (c0 + 2) * 4);
    const float4 w3 = *(const float4*)(linW + (c0 + 3) * 4);
    float4 t;
    t.x = fmaf(y.x, w0.x, fmaf(y.y, w1.x, fmaf(y.z, w2.x, y.w * w3.x)));
    t.y = fmaf(y.x, w0.y, fmaf(y.y, w1.y, fmaf(y.z, w2.y, y.w * w3.y)));
    t.z = fmaf(y.x, w0.z, fmaf(y.y, w1.z, fmaf(y.z, w2.z, y.w * w3.z)));
    t.w = fmaf(y.x, w0.w, fmaf(y.y, w1.w, fmaf(y.z, w2.w, y.w * w3.w)));
    t.x = dpp_add8(t.x); t.y = dpp_add8(t.y);
    t.z = dpp_add8(t.z); t.w = dpp_add8(t.w);

    if (q == 0) {
        const float4 lb = *(const float4*)linb;
        float4 o;
        o.x = t.x + lb.x; o.y = t.y + lb.y; o.z = t.z + lb.z; o.w = t.w + lb.w;
        *(float4*)(out + (size_t)n * 4) = o;
    }
}

// ---------------------------------------------------------------------------
extern "C" void kernel_launch(void* const* d_in, const int* in_sizes, int n_in,
                              void* d_out, int out_size, void* d_ws, size_t ws_size,
                              hipStream_t stream) {
    const float* x      = (const float*)d_in[0];
    const int*   ei     = (const int*)d_in[1];
    const float* ea     = (const float*)d_in[2];
    const float* l1_Wl  = (const float*)d_in[3];
    const float* l1_Wr  = (const float*)d_in[4];
    const float* l1_We  = (const float*)d_in[5];
    const float* l1_att = (const float*)d_in[6];
    const float* l1_b   = (const float*)d_in[7];
    const float* mid_Wl = (const float*)d_in[8];
    const float* mid_Wr = (const float*)d_in[9];
    const float* mid_We = (const float*)d_in[10];
    const float* mid_att= (const float*)d_in[11];
    const float* mid_b  = (const float*)d_in[12];
    const float* l10_Wl = (const float*)d_in[13];
    const float* l10_Wr = (const float*)d_in[14];
    const float* l10_We = (const float*)d_in[15];
    const float* l10_att= (const float*)d_in[16];
    const float* l10_b  = (const float*)d_in[17];
    const float* bn_g   = (const float*)d_in[18];
    const float* bn_b   = (const float*)d_in[19];
    const float* bn_m   = (const float*)d_in[20];
    const float* bn_v   = (const float*)d_in[21];
    const float* bn10_g = (const float*)d_in[22];
    const float* bn10_b = (const float*)d_in[23];
    const float* bn10_m = (const float*)d_in[24];
    const float* bn10_v = (const float*)d_in[25];
    const float* lin_W  = (const float*)d_in[26];
    const float* lin_b  = (const float*)d_in[27];

    char* ws = (char*)d_ws;
    auto take = [&](size_t bytes) { char* p = ws; ws += (bytes + 255) & ~size_t(255); return p; };
    int*   row_start  = (int*)  take(sizeof(int) * (NN + 1));
    int*   cursor     = (int*)  take(sizeof(int) * NN);
    int*   part       = (int*)  take(sizeof(int) * 256);
    int2*  epack      = (int2*) take(sizeof(int2) * EE);
    float* xlr        = (float*)take(sizeof(float) * (size_t)NN * 256);
    u16*   Ahi        = (u16*)  take(sizeof(u16) * (size_t)NN * 128);
    u16*   Alo        = (u16*)  take(sizeof(u16) * (size_t)NN * 128);
    u16*   Wthi       = (u16*)  take(sizeof(u16) * 9 * 256 * 128);
    u16*   Wtlo       = (u16*)  take(sizeof(u16) * 9 * 256 * 128);
    u16*   Wt10hi     = (u16*)  take(sizeof(u16) * 64 * 128);
    u16*   Wt10lo     = (u16*)  take(sizeof(u16) * 64 * 128);

    // --- CSR build ---
    hipMemsetAsync(cursor, 0, sizeof(int) * NN, stream);
    hist_kernel<<<EE / 256, 256, 0, stream>>>(ei + EE, cursor);
    scan_part<<<256, 256, 0, stream>>>(cursor, part);
    scan_final<<<256, 256, 0, stream>>>(cursor, part, row_start);
    scatter_kernel<<<EE / 256, 256, 0, stream>>>(ei, ea, cursor, epack);

    // --- one-time conversions (single fused dispatch) ---
    prep_all<<<(PREP_TOTAL + 255) / 256, 256, 0, stream>>>(
        x, l1_Wl, l1_Wr, mid_Wl, mid_Wr, l10_Wl, l10_Wr,
        Ahi, Alo, Wthi, Wtlo, Wt10hi, Wt10lo);

    const int GBM = (NN + 63) / 64;                 // 782 row-blocks

    // --- layer 1 ---
    gemm_mfma<<<GBM, 512, 0, stream>>>(Ahi, Alo, Wthi, Wtlo, xlr);
    node_agg_128<<<(NN * 64) / 256, 256, 0, stream>>>(
        xlr, row_start, epack, l1_We, l1_att, l1_b,
        bn_g, bn_b, bn_m, bn_v, Ahi, Alo);

    // --- layers 2-9 ---
    for (int i = 0; i < 8; ++i) {
        gemm_mfma<<<GBM, 512, 0, stream>>>(Ahi, Alo,
                                           Wthi + (size_t)(i + 1) * 32768,
                                           Wtlo + (size_t)(i + 1) * 32768, xlr);
        node_agg_128<<<(NN * 64) / 256, 256, 0, stream>>>(
            xlr, row_start, epack,
            mid_We + (size_t)i * 128, mid_att + (size_t)i * 128, mid_b + (size_t)i * 128,
            bn_g + (size_t)(i + 1) * 128, bn_b + (size_t)(i + 1) * 128,
            bn_m + (size_t)(i + 1) * 128, bn_v + (size_t)(i + 1) * 128,
            Ahi, Alo);
    }

    // --- layer 10: MFMA GEMM -> xlr[N][64], then aggregate+linear ---
    gemm_mfma_l10<<<GBM, 256, 0, stream>>>(Ahi, Alo, Wt10hi, Wt10lo, xlr);
    node_agg_l10<<<(NN * 32 + 255) / 256, 256, 0, stream>>>(
        xlr, row_start, epack, l10_We, l10_att, l10_b,
        bn10_g, bn10_b, bn10_m, bn10_v, lin_W, lin_b, (float*)d_out);
}